// Round 5
// baseline (286.909 us; speedup 1.0000x reference)
//
#include <hip/hip_runtime.h>

// TriPlane sampling with Morton-order spatial counting-sort.
// (1) one fused kernel transposes 6 planes [C,H,W] -> [H,W,C] into d_ws
// (2) counting-sort points into 32^3 Morton-ordered cells (zero/hist/scan/scatter)
// (3) sample in sorted order (3D-local -> L2-hit gathers); all 12 corner
//     gathers issued back-to-back for memory-level parallelism

#define CDIM 32
#define SGRID 32
#define NCELL (SGRID * SGRID * SGRID)
#define CHW 10000
#define FHW 160000
#define CBLK 157          // ceil(10000/64)
#define FBLK 2500         // 160000/64

struct PlanePtrs { const float* p[6]; };

// ---- fused transpose: [32,HW] -> [HW,32] for all 6 planes ----
__global__ void transpose_all(PlanePtrs in, float* __restrict__ out) {
    __shared__ float lds[64][33];
    const size_t CSZ = (size_t)CHW * CDIM;
    const size_t FSZ = (size_t)FHW * CDIM;

    int b = blockIdx.x;
    const float* src;
    float* dst;
    int HW, local;
    if (b < 3 * CBLK) {
        int plane = b / CBLK; local = b - plane * CBLK;
        src = in.p[plane]; dst = out + (size_t)plane * CSZ; HW = CHW;
    } else {
        b -= 3 * CBLK;
        int plane = b / FBLK; local = b - plane * FBLK;
        src = in.p[3 + plane]; dst = out + 3 * CSZ + (size_t)plane * FSZ; HW = FHW;
    }

    int p0  = local * 64;
    int tid = threadIdx.x;
    int pi  = tid & 63;
    int cg  = tid >> 6;
#pragma unroll
    for (int i = 0; i < 8; ++i) {
        int c = cg * 8 + i;
        int p = p0 + pi;
        float v = (p < HW) ? src[(size_t)c * HW + p] : 0.0f;
        lds[pi][c] = v;
    }
    __syncthreads();
    int c2 = tid & 31;
    int pj = tid >> 5;
#pragma unroll
    for (int i = 0; i < 8; ++i) {
        int p = pj + i * 8;
        if (p0 + p < HW)
            dst[(size_t)(p0 + p) * CDIM + c2] = lds[p][c2];
    }
}

__global__ void zero_cells(int4* __restrict__ cells4) {
    int i = blockIdx.x * blockDim.x + threadIdx.x;   // 8192 int4
    cells4[i] = make_int4(0, 0, 0, 0);
}

// ---- Morton cell index: 3D locality along the sorted order ----
__device__ __forceinline__ int spread3(int v) {
    v = (v | (v << 16)) & 0x030000FF;
    v = (v | (v << 8))  & 0x0300F00F;
    v = (v | (v << 4))  & 0x030C30C3;
    v = (v | (v << 2))  & 0x09249249;
    return v;
}

__device__ __forceinline__ int cell_of(float x, float y, float z) {
    int cx = (int)((x + 4.0f) * 4.0f);
    int cy = (int)((y + 4.0f) * 4.0f);
    int cz = (int)((z + 4.0f) * 4.0f);
    cx = min(SGRID - 1, max(0, cx));
    cy = min(SGRID - 1, max(0, cy));
    cz = min(SGRID - 1, max(0, cz));
    return spread3(cx) | (spread3(cy) << 1) | (spread3(cz) << 2);
}

__global__ void hist_kernel(const float* __restrict__ xyz,
                            int* __restrict__ cells, int n) {
    int i = blockIdx.x * blockDim.x + threadIdx.x;
    if (i >= n) return;
    float x = xyz[3 * (size_t)i + 0];
    float y = xyz[3 * (size_t)i + 1];
    float z = xyz[3 * (size_t)i + 2];
    atomicAdd(&cells[cell_of(x, y, z)], 1);
}

// in-place exclusive scan of cells[NCELL]; 1 block x 1024 thr x 32 cells (int4)
__global__ void scan_cells(int* __restrict__ cells) {
    __shared__ int lds[1024];
    int t = threadIdx.x;
    int4* c4p = (int4*)cells;
    int4 v[8];
    int s = 0;
#pragma unroll
    for (int i = 0; i < 8; ++i) {
        v[i] = c4p[t * 8 + i];
        s += v[i].x + v[i].y + v[i].z + v[i].w;
    }
    lds[t] = s;
    __syncthreads();
    for (int off = 1; off < 1024; off <<= 1) {
        int u = 0;
        if (t >= off) u = lds[t - off];
        __syncthreads();
        if (t >= off) lds[t] += u;
        __syncthreads();
    }
    int prefix = (t == 0) ? 0 : lds[t - 1];
#pragma unroll
    for (int i = 0; i < 8; ++i) {
        int a = v[i].x, b = v[i].y, c = v[i].z, d = v[i].w;
        v[i].x = prefix;
        v[i].y = prefix + a;
        v[i].z = prefix + a + b;
        v[i].w = prefix + a + b + c;
        prefix += a + b + c + d;
        c4p[t * 8 + i] = v[i];
    }
}

__global__ void scatter_kernel(const float* __restrict__ xyz,
                               int* __restrict__ offs,
                               float4* __restrict__ sortedg, int n) {
    int i = blockIdx.x * blockDim.x + threadIdx.x;
    if (i >= n) return;
    float x = xyz[3 * (size_t)i + 0];
    float y = xyz[3 * (size_t)i + 1];
    float z = xyz[3 * (size_t)i + 2];
    int pos = atomicAdd(&offs[cell_of(x, y, z)], 1);
    float4 v;
    v.x = (x + 4.0f) * 0.25f - 1.0f;
    v.y = (y + 4.0f) * 0.25f - 1.0f;
    v.z = (z + 4.0f) * 0.25f - 1.0f;
    v.w = __int_as_float(i);
    sortedg[pos] = v;
}

// ---- bilinear corner addresses for one plane ----
struct Corners {
    const float4 *p00, *p01, *p10, *p11;
    float wx, wy;
};

__device__ __forceinline__ Corners mk_corners(const float* __restrict__ base,
                                              int R, float u, float v, int c4) {
    float s = 0.5f * (float)(R - 1);
    float x = (u + 1.0f) * s;
    float y = (v + 1.0f) * s;
    float rm1 = (float)(R - 1);
    x = fminf(fmaxf(x, 0.0f), rm1);
    y = fminf(fmaxf(y, 0.0f), rm1);
    float x0f = floorf(x), y0f = floorf(y);
    int x0 = (int)x0f, y0 = (int)y0f;
    int x1 = min(x0 + 1, R - 1);
    int y1 = min(y0 + 1, R - 1);
    Corners c;
    c.wx = x - x0f;
    c.wy = y - y0f;
    const float* r0 = base + ((size_t)y0 * R) * CDIM + c4;
    const float* r1 = base + ((size_t)y1 * R) * CDIM + c4;
    c.p00 = (const float4*)(r0 + (size_t)x0 * CDIM);
    c.p01 = (const float4*)(r0 + (size_t)x1 * CDIM);
    c.p10 = (const float4*)(r1 + (size_t)x0 * CDIM);
    c.p11 = (const float4*)(r1 + (size_t)x1 * CDIM);
    return c;
}

__device__ __forceinline__ float4 blend(float4 a, float4 b, float4 c, float4 d,
                                        float wx, float wy) {
    float w00 = (1.0f - wx) * (1.0f - wy);
    float w01 = wx * (1.0f - wy);
    float w10 = (1.0f - wx) * wy;
    float w11 = wx * wy;
    float4 r;
    r.x = a.x * w00 + b.x * w01 + c.x * w10 + d.x * w11;
    r.y = a.y * w00 + b.y * w01 + c.y * w10 + d.y * w11;
    r.z = a.z * w00 + b.z * w01 + c.z * w10 + d.z * w11;
    r.w = a.w * w00 + b.w * w01 + c.w * w10 + d.w * w11;
    return r;
}

// ---- sampler: 16 threads/point, all 12 gathers issued back-to-back ----
__global__ void triplane_sample(const float4* __restrict__ sortedg,
                                const float* __restrict__ planes,
                                float* __restrict__ out, int n_pts) {
    int nwg  = gridDim.x;
    int orig = blockIdx.x;
    int xcd = orig & 7, local = orig >> 3;
    int q = nwg >> 3, r = nwg & 7;
    int wg = (xcd < r ? xcd * (q + 1) : r * (q + 1) + (xcd - r) * q) + local;

    int tid = wg * 256 + (int)threadIdx.x;
    int i = tid >> 4;
    if (i >= n_pts) return;
    int l     = tid & 15;
    int level = l >> 3;
    int c4    = (l & 7) * 4;

    float4 g = sortedg[i];
    int n_orig = __float_as_int(g.w);

    const size_t CSZ = (size_t)CHW * CDIM;
    const size_t FSZ = (size_t)FHW * CDIM;
    const float* base;
    int R;
    size_t psz;
    if (level == 0) { base = planes;           R = 100; psz = CSZ; }
    else            { base = planes + 3 * CSZ; R = 400; psz = FSZ; }

    // Phase 1: all address math
    Corners cxy = mk_corners(base,           R, g.x, g.y, c4);
    Corners cxz = mk_corners(base + psz,     R, g.x, g.z, c4);
    Corners cyz = mk_corners(base + 2 * psz, R, g.y, g.z, c4);

    // Phase 2: issue all 12 gathers (independent -> overlapped latency)
    float4 a0 = *cxy.p00, a1 = *cxy.p01, a2 = *cxy.p10, a3 = *cxy.p11;
    float4 b0 = *cxz.p00, b1 = *cxz.p01, b2 = *cxz.p10, b3 = *cxz.p11;
    float4 d0 = *cyz.p00, d1 = *cyz.p01, d2 = *cyz.p10, d3 = *cyz.p11;

    // Phase 3: blend + sum
    float4 fxy = blend(a0, a1, a2, a3, cxy.wx, cxy.wy);
    float4 fxz = blend(b0, b1, b2, b3, cxz.wx, cxz.wy);
    float4 fyz = blend(d0, d1, d2, d3, cyz.wx, cyz.wy);

    float4 o;
    o.x = fxy.x + fxz.x + fyz.x;
    o.y = fxy.y + fxz.y + fyz.y;
    o.z = fxy.z + fxz.z + fyz.z;
    o.w = fxy.w + fxz.w + fyz.w;

    *(float4*)(out + (size_t)n_orig * 64 + level * 32 + c4) = o;
}

extern "C" void kernel_launch(void* const* d_in, const int* in_sizes, int n_in,
                              void* d_out, int out_size, void* d_ws, size_t ws_size,
                              hipStream_t stream) {
    const float* xyz = (const float*)d_in[0];
    int n = in_sizes[0] / 3;

    const size_t CSZ = (size_t)CHW * CDIM;
    const size_t FSZ = (size_t)FHW * CDIM;
    const size_t PLANES = 3 * CSZ + 3 * FSZ;  // floats

    float*  ws      = (float*)d_ws;
    int*    cells   = (int*)(ws + PLANES);
    float4* sortedg = (float4*)((char*)d_ws + PLANES * 4 + (size_t)NCELL * 4);

    dim3 blk(256);
    PlanePtrs pp;
    for (int k = 0; k < 6; ++k) pp.p[k] = (const float*)d_in[1 + k];
    transpose_all<<<3 * CBLK + 3 * FBLK, blk, 0, stream>>>(pp, ws);

    zero_cells<<<NCELL / 4 / 256, blk, 0, stream>>>((int4*)cells);
    hist_kernel<<<(n + 255) / 256, blk, 0, stream>>>(xyz, cells, n);
    scan_cells<<<1, 1024, 0, stream>>>(cells);
    scatter_kernel<<<(n + 255) / 256, blk, 0, stream>>>(xyz, cells, sortedg, n);

    long long total_threads = (long long)n * 16;
    int nblk = (int)((total_threads + 255) / 256);
    triplane_sample<<<nblk, blk, 0, stream>>>(sortedg, ws, (float*)d_out, n);
}

// Round 7
// 257.190 us; speedup vs baseline: 1.1156x; 1.1156x over previous
//
#include <hip/hip_runtime.h>

// TriPlane sampling, Morton counting-sort, bf16 transposed planes.
// (1) fused kernel: transpose 6 planes [C,H,W]f32 -> [H,W,C]bf16 + histogram
// (2) scan + scatter (counting sort into 32^3 Morton cells)
// (3) sample sorted points: 8 threads/pt, 12x 16B bf16 gathers, f32 blend

#define CDIM 32
#define SGRID 32
#define NCELL (SGRID * SGRID * SGRID)
#define CHW 10000
#define FHW 160000
#define CBLK 157          // ceil(10000/64)
#define FBLK 2500         // 160000/64
#define TRB (3 * CBLK + 3 * FBLK)

struct PlanePtrs { const float* p[6]; };

__device__ __forceinline__ unsigned bf16rn(float f) {  // RNE f32->bf16 bits
    unsigned u = __float_as_uint(f);
    return (u + 0x7FFFu + ((u >> 16) & 1u)) >> 16;
}

// ---- Morton cell index ----
__device__ __forceinline__ int spread3(int v) {
    v = (v | (v << 16)) & 0x030000FF;
    v = (v | (v << 8))  & 0x0300F00F;
    v = (v | (v << 4))  & 0x030C30C3;
    v = (v | (v << 2))  & 0x09249249;
    return v;
}

__device__ __forceinline__ int cell_of(float x, float y, float z) {
    int cx = (int)((x + 4.0f) * 4.0f);
    int cy = (int)((y + 4.0f) * 4.0f);
    int cz = (int)((z + 4.0f) * 4.0f);
    cx = min(SGRID - 1, max(0, cx));
    cy = min(SGRID - 1, max(0, cy));
    cz = min(SGRID - 1, max(0, cz));
    return spread3(cx) | (spread3(cy) << 1) | (spread3(cz) << 2);
}

__global__ void zero_cells(int4* __restrict__ cells4) {
    int i = blockIdx.x * blockDim.x + threadIdx.x;   // 8192 int4
    cells4[i] = make_int4(0, 0, 0, 0);
}

// ---- fused: blocks [0,TRB) transpose planes to bf16; rest do histogram ----
__global__ void transpose_hist(PlanePtrs in, unsigned* __restrict__ outp,
                               const float* __restrict__ xyz,
                               int* __restrict__ cells, int n) {
    __shared__ float lds[64][33];
    int b = blockIdx.x;
    int tid = threadIdx.x;

    if (b >= TRB) {
        // ---- histogram: 4 points per thread, float4-vectorized ----
        int t = (b - TRB) * 256 + tid;            // thread over point-quads
        int i0 = t * 4;
        if (i0 >= n) return;
        const float4* x4 = (const float4*)xyz;    // xyz is [n,3] -> 3 float4 per 4 pts
        float4 v0 = x4[t * 3 + 0];
        float4 v1 = x4[t * 3 + 1];
        float4 v2 = x4[t * 3 + 2];
        float px[4] = {v0.x, v0.w, v1.z, v2.y};
        float py[4] = {v0.y, v1.x, v1.w, v2.z};
        float pz[4] = {v0.z, v1.y, v2.x, v2.w};
#pragma unroll
        for (int k = 0; k < 4; ++k)
            if (i0 + k < n) atomicAdd(&cells[cell_of(px[k], py[k], pz[k])], 1);
        return;
    }

    // ---- transpose [32,HW]f32 -> [HW,32]bf16 ----
    const size_t CSZ = (size_t)CHW * CDIM;
    const size_t FSZ = (size_t)FHW * CDIM;
    const float* src;
    unsigned* dst;   // packed bf16 pairs (uint = 2 channels)
    int HW, local;
    if (b < 3 * CBLK) {
        int plane = b / CBLK; local = b - plane * CBLK;
        src = in.p[plane];
        dst = outp + (size_t)plane * (CSZ / 2);
        HW = CHW;
    } else {
        b -= 3 * CBLK;
        int plane = b / FBLK; local = b - plane * FBLK;
        src = in.p[3 + plane];
        dst = outp + (3 * CSZ + (size_t)plane * FSZ) / 2;
        HW = FHW;
    }

    int p0 = local * 64;
    int pi = tid & 63;
    int cg = tid >> 6;
#pragma unroll
    for (int i = 0; i < 8; ++i) {
        int c = cg * 8 + i;
        int p = p0 + pi;
        float v = (p < HW) ? src[(size_t)c * HW + p] : 0.0f;
        lds[pi][c] = v;
    }
    __syncthreads();
    int cp = tid & 15;           // channel pair 0..15
    int pj = tid >> 4;           // 0..15
#pragma unroll
    for (int i = 0; i < 4; ++i) {
        int p = pj + i * 16;     // 0..63
        if (p0 + p < HW) {
            unsigned lo = bf16rn(lds[p][2 * cp]);
            unsigned hi = bf16rn(lds[p][2 * cp + 1]);
            dst[(size_t)(p0 + p) * 16 + cp] = lo | (hi << 16);
        }
    }
}

// in-place exclusive scan of cells[NCELL]; 1 block x 1024 thr x 32 cells (int4)
__global__ void scan_cells(int* __restrict__ cells) {
    __shared__ int lds[1024];
    int t = threadIdx.x;
    int4* c4p = (int4*)cells;
    int4 v[8];
    int s = 0;
#pragma unroll
    for (int i = 0; i < 8; ++i) {
        v[i] = c4p[t * 8 + i];
        s += v[i].x + v[i].y + v[i].z + v[i].w;
    }
    lds[t] = s;
    __syncthreads();
    for (int off = 1; off < 1024; off <<= 1) {
        int u = 0;
        if (t >= off) u = lds[t - off];
        __syncthreads();
        if (t >= off) lds[t] += u;
        __syncthreads();
    }
    int prefix = (t == 0) ? 0 : lds[t - 1];
#pragma unroll
    for (int i = 0; i < 8; ++i) {
        int a = v[i].x, bb = v[i].y, c = v[i].z, d = v[i].w;
        v[i].x = prefix;
        v[i].y = prefix + a;
        v[i].z = prefix + a + bb;
        v[i].w = prefix + a + bb + c;
        prefix += a + bb + c + d;
        c4p[t * 8 + i] = v[i];
    }
}

__global__ void scatter_kernel(const float* __restrict__ xyz,
                               int* __restrict__ offs,
                               float4* __restrict__ sortedg, int n) {
    int t = blockIdx.x * blockDim.x + threadIdx.x;
    int i0 = t * 4;
    if (i0 >= n) return;
    const float4* x4 = (const float4*)xyz;
    float4 v0 = x4[t * 3 + 0];
    float4 v1 = x4[t * 3 + 1];
    float4 v2 = x4[t * 3 + 2];
    float px[4] = {v0.x, v0.w, v1.z, v2.y};
    float py[4] = {v0.y, v1.x, v1.w, v2.z};
    float pz[4] = {v0.z, v1.y, v2.x, v2.w};
#pragma unroll
    for (int k = 0; k < 4; ++k) {
        int i = i0 + k;
        if (i >= n) break;
        int pos = atomicAdd(&offs[cell_of(px[k], py[k], pz[k])], 1);
        float4 v;
        v.x = (px[k] + 4.0f) * 0.25f - 1.0f;
        v.y = (py[k] + 4.0f) * 0.25f - 1.0f;
        v.z = (pz[k] + 4.0f) * 0.25f - 1.0f;
        v.w = __int_as_float(i);
        sortedg[pos] = v;
    }
}

// ---- bilinear corner addresses for one bf16 plane (8 channels/thread) ----
struct CornersB {
    const uint4 *p00, *p01, *p10, *p11;
    float wx, wy;
};

__device__ __forceinline__ CornersB mk_corners(const unsigned* __restrict__ base,
                                               int R, float u, float v, int c8) {
    float s = 0.5f * (float)(R - 1);
    float x = (u + 1.0f) * s;
    float y = (v + 1.0f) * s;
    float rm1 = (float)(R - 1);
    x = fminf(fmaxf(x, 0.0f), rm1);
    y = fminf(fmaxf(y, 0.0f), rm1);
    float x0f = floorf(x), y0f = floorf(y);
    int x0 = (int)x0f, y0 = (int)y0f;
    int x1 = min(x0 + 1, R - 1);
    int y1 = min(y0 + 1, R - 1);
    CornersB c;
    c.wx = x - x0f;
    c.wy = y - y0f;
    // texel = 16 uints (32 bf16); thread's slice = 4 uints at c8/2
    const unsigned* r0 = base + ((size_t)y0 * R) * 16 + c8 / 2;
    const unsigned* r1 = base + ((size_t)y1 * R) * 16 + c8 / 2;
    c.p00 = (const uint4*)(r0 + (size_t)x0 * 16);
    c.p01 = (const uint4*)(r0 + (size_t)x1 * 16);
    c.p10 = (const uint4*)(r1 + (size_t)x0 * 16);
    c.p11 = (const uint4*)(r1 + (size_t)x1 * 16);
    return c;
}

__device__ __forceinline__ void acc8(float* acc, uint4 u, float w) {
#pragma unroll
    for (int j = 0; j < 4; ++j) {
        unsigned word = (&u.x)[j];
        float lo = __uint_as_float(word << 16);
        float hi = __uint_as_float(word & 0xFFFF0000u);
        acc[2 * j]     += lo * w;
        acc[2 * j + 1] += hi * w;
    }
}

__device__ __forceinline__ void blend8(float* acc, uint4 a, uint4 b, uint4 c,
                                       uint4 d, float wx, float wy) {
    float w00 = (1.0f - wx) * (1.0f - wy);
    float w01 = wx * (1.0f - wy);
    float w10 = (1.0f - wx) * wy;
    float w11 = wx * wy;
    acc8(acc, a, w00);
    acc8(acc, b, w01);
    acc8(acc, c, w10);
    acc8(acc, d, w11);
}

// ---- sampler: 8 threads/point (level x 8-channel group), XCD-swizzled ----
__global__ void triplane_sample(const float4* __restrict__ sortedg,
                                const unsigned* __restrict__ planes,
                                float* __restrict__ out, int n_pts) {
    int nwg  = gridDim.x;
    int orig = blockIdx.x;
    int xcd = orig & 7, local = orig >> 3;
    int q = nwg >> 3, r = nwg & 7;
    int wg = (xcd < r ? xcd * (q + 1) : r * (q + 1) + (xcd - r) * q) + local;

    int tid = wg * 256 + (int)threadIdx.x;
    int i = tid >> 3;
    if (i >= n_pts) return;
    int l     = tid & 7;
    int level = l >> 2;
    int c8    = (l & 3) * 8;

    float4 g = sortedg[i];
    int n_orig = __float_as_int(g.w);

    const size_t CSZ2 = (size_t)CHW * CDIM / 2;   // uints per coarse plane
    const size_t FSZ2 = (size_t)FHW * CDIM / 2;
    const unsigned* base;
    int R;
    size_t psz;
    if (level == 0) { base = planes;            R = 100; psz = CSZ2; }
    else            { base = planes + 3 * CSZ2; R = 400; psz = FSZ2; }

    CornersB cxy = mk_corners(base,           R, g.x, g.y, c8);
    CornersB cxz = mk_corners(base + psz,     R, g.x, g.z, c8);
    CornersB cyz = mk_corners(base + 2 * psz, R, g.y, g.z, c8);

    uint4 a0 = *cxy.p00, a1 = *cxy.p01, a2 = *cxy.p10, a3 = *cxy.p11;
    uint4 b0 = *cxz.p00, b1 = *cxz.p01, b2 = *cxz.p10, b3 = *cxz.p11;
    uint4 d0 = *cyz.p00, d1 = *cyz.p01, d2 = *cyz.p10, d3 = *cyz.p11;

    float acc[8] = {0, 0, 0, 0, 0, 0, 0, 0};
    blend8(acc, a0, a1, a2, a3, cxy.wx, cxy.wy);
    blend8(acc, b0, b1, b2, b3, cxz.wx, cxz.wy);
    blend8(acc, d0, d1, d2, d3, cyz.wx, cyz.wy);

    float* o = out + (size_t)n_orig * 64 + level * 32 + c8;
    *(float4*)(o)     = make_float4(acc[0], acc[1], acc[2], acc[3]);
    *(float4*)(o + 4) = make_float4(acc[4], acc[5], acc[6], acc[7]);
}

extern "C" void kernel_launch(void* const* d_in, const int* in_sizes, int n_in,
                              void* d_out, int out_size, void* d_ws, size_t ws_size,
                              hipStream_t stream) {
    const float* xyz = (const float*)d_in[0];
    int n = in_sizes[0] / 3;

    const size_t CSZ = (size_t)CHW * CDIM;
    const size_t FSZ = (size_t)FHW * CDIM;
    const size_t PLANE_UINTS = (3 * CSZ + 3 * FSZ) / 2;   // packed bf16 pairs

    unsigned* planesb = (unsigned*)d_ws;
    int*      cells   = (int*)(planesb + PLANE_UINTS);
    float4*   sortedg = (float4*)((char*)(cells) + (size_t)NCELL * 4);

    dim3 blk(256);
    PlanePtrs pp;
    for (int k = 0; k < 6; ++k) pp.p[k] = (const float*)d_in[1 + k];

    zero_cells<<<NCELL / 4 / 256, blk, 0, stream>>>((int4*)cells);

    int histblk = (n + 1023) / 1024;   // 4 pts/thread
    transpose_hist<<<TRB + histblk, blk, 0, stream>>>(pp, planesb, xyz, cells, n);

    scan_cells<<<1, 1024, 0, stream>>>(cells);
    scatter_kernel<<<histblk, blk, 0, stream>>>(xyz, cells, sortedg, n);

    long long total_threads = (long long)n * 8;
    int nblk = (int)((total_threads + 255) / 256);
    triplane_sample<<<nblk, blk, 0, stream>>>(sortedg, planesb, (float*)d_out, n);
}

// Round 9
// 241.439 us; speedup vs baseline: 1.1883x; 1.0652x over previous
//
#include <hip/hip_runtime.h>

// TriPlane sampling, Morton counting-sort, bf16 transposed planes.
// (1) fused kernel: transpose 6 planes [C,H,W]f32 -> [H,W,C]bf16 + histogram
// (2) scan + scatter (counting sort into 32^3 Morton cells)
// (3) sample sorted points: wave-pure levels (16 pts x 4 slices per wave),
//     12x 16B bf16 gathers, f32 blend, NONTEMPORAL output stores (keep L2
//     for plane gathers; the 256MB output stream is write-once).

#define CDIM 32
#define SGRID 32
#define NCELL (SGRID * SGRID * SGRID)
#define CHW 10000
#define FHW 160000
#define CBLK 157          // ceil(10000/64)
#define FBLK 2500         // 160000/64
#define TRB (3 * CBLK + 3 * FBLK)

typedef float  nfloat4 __attribute__((ext_vector_type(4)));  // nontemporal-safe

struct PlanePtrs { const float* p[6]; };

__device__ __forceinline__ unsigned bf16rn(float f) {  // RNE f32->bf16 bits
    unsigned u = __float_as_uint(f);
    return (u + 0x7FFFu + ((u >> 16) & 1u)) >> 16;
}

// ---- Morton cell index ----
__device__ __forceinline__ int spread3(int v) {
    v = (v | (v << 16)) & 0x030000FF;
    v = (v | (v << 8))  & 0x0300F00F;
    v = (v | (v << 4))  & 0x030C30C3;
    v = (v | (v << 2))  & 0x09249249;
    return v;
}

__device__ __forceinline__ int cell_of(float x, float y, float z) {
    int cx = (int)((x + 4.0f) * 4.0f);
    int cy = (int)((y + 4.0f) * 4.0f);
    int cz = (int)((z + 4.0f) * 4.0f);
    cx = min(SGRID - 1, max(0, cx));
    cy = min(SGRID - 1, max(0, cy));
    cz = min(SGRID - 1, max(0, cz));
    return spread3(cx) | (spread3(cy) << 1) | (spread3(cz) << 2);
}

__global__ void zero_cells(int4* __restrict__ cells4) {
    int i = blockIdx.x * blockDim.x + threadIdx.x;   // 8192 int4
    cells4[i] = make_int4(0, 0, 0, 0);
}

// ---- fused: blocks [0,TRB) transpose planes to bf16; rest do histogram ----
__global__ void transpose_hist(PlanePtrs in, unsigned* __restrict__ outp,
                               const float* __restrict__ xyz,
                               int* __restrict__ cells, int n) {
    __shared__ float lds[64][33];
    int b = blockIdx.x;
    int tid = threadIdx.x;

    if (b >= TRB) {
        // ---- histogram: 4 points per thread, float4-vectorized ----
        int t = (b - TRB) * 256 + tid;
        int i0 = t * 4;
        if (i0 >= n) return;
        const nfloat4* x4 = (const nfloat4*)xyz;
        nfloat4 v0 = __builtin_nontemporal_load(&x4[t * 3 + 0]);
        nfloat4 v1 = __builtin_nontemporal_load(&x4[t * 3 + 1]);
        nfloat4 v2 = __builtin_nontemporal_load(&x4[t * 3 + 2]);
        float px[4] = {v0.x, v0.w, v1.z, v2.y};
        float py[4] = {v0.y, v1.x, v1.w, v2.z};
        float pz[4] = {v0.z, v1.y, v2.x, v2.w};
#pragma unroll
        for (int k = 0; k < 4; ++k)
            if (i0 + k < n) atomicAdd(&cells[cell_of(px[k], py[k], pz[k])], 1);
        return;
    }

    // ---- transpose [32,HW]f32 -> [HW,32]bf16 ----
    const size_t CSZ = (size_t)CHW * CDIM;
    const size_t FSZ = (size_t)FHW * CDIM;
    const float* src;
    unsigned* dst;   // packed bf16 pairs (uint = 2 channels)
    int HW, local;
    if (b < 3 * CBLK) {
        int plane = b / CBLK; local = b - plane * CBLK;
        src = in.p[plane];
        dst = outp + (size_t)plane * (CSZ / 2);
        HW = CHW;
    } else {
        b -= 3 * CBLK;
        int plane = b / FBLK; local = b - plane * FBLK;
        src = in.p[3 + plane];
        dst = outp + (3 * CSZ + (size_t)plane * FSZ) / 2;
        HW = FHW;
    }

    int p0 = local * 64;
    int pi = tid & 63;
    int cg = tid >> 6;
#pragma unroll
    for (int i = 0; i < 8; ++i) {
        int c = cg * 8 + i;
        int p = p0 + pi;
        float v = (p < HW) ? src[(size_t)c * HW + p] : 0.0f;
        lds[pi][c] = v;
    }
    __syncthreads();
    int cp = tid & 15;           // channel pair 0..15
    int pj = tid >> 4;           // 0..15
#pragma unroll
    for (int i = 0; i < 4; ++i) {
        int p = pj + i * 16;     // 0..63
        if (p0 + p < HW) {
            unsigned lo = bf16rn(lds[p][2 * cp]);
            unsigned hi = bf16rn(lds[p][2 * cp + 1]);
            dst[(size_t)(p0 + p) * 16 + cp] = lo | (hi << 16);
        }
    }
}

// in-place exclusive scan of cells[NCELL]; 1 block x 1024 thr x 32 cells (int4)
__global__ void scan_cells(int* __restrict__ cells) {
    __shared__ int lds[1024];
    int t = threadIdx.x;
    int4* c4p = (int4*)cells;
    int4 v[8];
    int s = 0;
#pragma unroll
    for (int i = 0; i < 8; ++i) {
        v[i] = c4p[t * 8 + i];
        s += v[i].x + v[i].y + v[i].z + v[i].w;
    }
    lds[t] = s;
    __syncthreads();
    for (int off = 1; off < 1024; off <<= 1) {
        int u = 0;
        if (t >= off) u = lds[t - off];
        __syncthreads();
        if (t >= off) lds[t] += u;
        __syncthreads();
    }
    int prefix = (t == 0) ? 0 : lds[t - 1];
#pragma unroll
    for (int i = 0; i < 8; ++i) {
        int a = v[i].x, bb = v[i].y, c = v[i].z, d = v[i].w;
        v[i].x = prefix;
        v[i].y = prefix + a;
        v[i].z = prefix + a + bb;
        v[i].w = prefix + a + bb + c;
        prefix += a + bb + c + d;
        c4p[t * 8 + i] = v[i];
    }
}

__global__ void scatter_kernel(const float* __restrict__ xyz,
                               int* __restrict__ offs,
                               float4* __restrict__ sortedg, int n) {
    int t = blockIdx.x * blockDim.x + threadIdx.x;
    int i0 = t * 4;
    if (i0 >= n) return;
    const nfloat4* x4 = (const nfloat4*)xyz;
    nfloat4 v0 = __builtin_nontemporal_load(&x4[t * 3 + 0]);
    nfloat4 v1 = __builtin_nontemporal_load(&x4[t * 3 + 1]);
    nfloat4 v2 = __builtin_nontemporal_load(&x4[t * 3 + 2]);
    float px[4] = {v0.x, v0.w, v1.z, v2.y};
    float py[4] = {v0.y, v1.x, v1.w, v2.z};
    float pz[4] = {v0.z, v1.y, v2.x, v2.w};
#pragma unroll
    for (int k = 0; k < 4; ++k) {
        int i = i0 + k;
        if (i >= n) break;
        int pos = atomicAdd(&offs[cell_of(px[k], py[k], pz[k])], 1);
        float4 v;
        v.x = (px[k] + 4.0f) * 0.25f - 1.0f;
        v.y = (py[k] + 4.0f) * 0.25f - 1.0f;
        v.z = (pz[k] + 4.0f) * 0.25f - 1.0f;
        v.w = __int_as_float(i);
        sortedg[pos] = v;
    }
}

// ---- bilinear corner addresses for one bf16 plane (8 channels/thread) ----
struct CornersB {
    const uint4 *p00, *p01, *p10, *p11;
    float wx, wy;
};

__device__ __forceinline__ CornersB mk_corners(const unsigned* __restrict__ base,
                                               int R, float u, float v, int c8) {
    float s = 0.5f * (float)(R - 1);
    float x = (u + 1.0f) * s;
    float y = (v + 1.0f) * s;
    float rm1 = (float)(R - 1);
    x = fminf(fmaxf(x, 0.0f), rm1);
    y = fminf(fmaxf(y, 0.0f), rm1);
    float x0f = floorf(x), y0f = floorf(y);
    int x0 = (int)x0f, y0 = (int)y0f;
    int x1 = min(x0 + 1, R - 1);
    int y1 = min(y0 + 1, R - 1);
    CornersB c;
    c.wx = x - x0f;
    c.wy = y - y0f;
    const unsigned* r0 = base + ((size_t)y0 * R) * 16 + c8 / 2;
    const unsigned* r1 = base + ((size_t)y1 * R) * 16 + c8 / 2;
    c.p00 = (const uint4*)(r0 + (size_t)x0 * 16);
    c.p01 = (const uint4*)(r0 + (size_t)x1 * 16);
    c.p10 = (const uint4*)(r1 + (size_t)x0 * 16);
    c.p11 = (const uint4*)(r1 + (size_t)x1 * 16);
    return c;
}

__device__ __forceinline__ void acc8(float* acc, uint4 u, float w) {
#pragma unroll
    for (int j = 0; j < 4; ++j) {
        unsigned word = (&u.x)[j];
        float lo = __uint_as_float(word << 16);
        float hi = __uint_as_float(word & 0xFFFF0000u);
        acc[2 * j]     += lo * w;
        acc[2 * j + 1] += hi * w;
    }
}

__device__ __forceinline__ void blend8(float* acc, uint4 a, uint4 b, uint4 c,
                                       uint4 d, float wx, float wy) {
    float w00 = (1.0f - wx) * (1.0f - wy);
    float w01 = wx * (1.0f - wy);
    float w10 = (1.0f - wx) * wy;
    float w11 = wx * wy;
    acc8(acc, a, w00);
    acc8(acc, b, w01);
    acc8(acc, c, w10);
    acc8(acc, d, w11);
}

// ---- sampler: 32 pts/block; each 64-lane wave is LEVEL-PURE:
//      wave w (0..3): level = w&1, points = base + (w>>1)*16 + (lane>>2),
//      channel slice c8 = (lane&3)*8. Output via nontemporal stores. ----
__global__ void triplane_sample(const float4* __restrict__ sortedg,
                                const unsigned* __restrict__ planes,
                                float* __restrict__ out, int n_pts) {
    int nwg  = gridDim.x;
    int orig = blockIdx.x;
    int xcd = orig & 7, local = orig >> 3;
    int q = nwg >> 3, r = nwg & 7;
    int wg = (xcd < r ? xcd * (q + 1) : r * (q + 1) + (xcd - r) * q) + local;

    int wave = (int)threadIdx.x >> 6;
    int lane = (int)threadIdx.x & 63;
    int level = wave & 1;
    int i = wg * 32 + (wave >> 1) * 16 + (lane >> 2);
    if (i >= n_pts) return;
    int c8 = (lane & 3) * 8;

    float4 g = sortedg[i];
    int n_orig = __float_as_int(g.w);

    const size_t CSZ2 = (size_t)CHW * CDIM / 2;   // uints per coarse plane
    const size_t FSZ2 = (size_t)FHW * CDIM / 2;
    const unsigned* base;
    int R;
    size_t psz;
    if (level == 0) { base = planes;            R = 100; psz = CSZ2; }
    else            { base = planes + 3 * CSZ2; R = 400; psz = FSZ2; }

    CornersB cxy = mk_corners(base,           R, g.x, g.y, c8);
    CornersB cxz = mk_corners(base + psz,     R, g.x, g.z, c8);
    CornersB cyz = mk_corners(base + 2 * psz, R, g.y, g.z, c8);

    uint4 a0 = *cxy.p00, a1 = *cxy.p01, a2 = *cxy.p10, a3 = *cxy.p11;
    uint4 b0 = *cxz.p00, b1 = *cxz.p01, b2 = *cxz.p10, b3 = *cxz.p11;
    uint4 d0 = *cyz.p00, d1 = *cyz.p01, d2 = *cyz.p10, d3 = *cyz.p11;

    float acc[8] = {0, 0, 0, 0, 0, 0, 0, 0};
    blend8(acc, a0, a1, a2, a3, cxy.wx, cxy.wy);
    blend8(acc, b0, b1, b2, b3, cxz.wx, cxz.wy);
    blend8(acc, d0, d1, d2, d3, cyz.wx, cyz.wy);

    float* o = out + (size_t)n_orig * 64 + level * 32 + c8;
    nfloat4 lo4 = {acc[0], acc[1], acc[2], acc[3]};
    nfloat4 hi4 = {acc[4], acc[5], acc[6], acc[7]};
    __builtin_nontemporal_store(lo4, (nfloat4*)o);
    __builtin_nontemporal_store(hi4, (nfloat4*)(o + 4));
}

extern "C" void kernel_launch(void* const* d_in, const int* in_sizes, int n_in,
                              void* d_out, int out_size, void* d_ws, size_t ws_size,
                              hipStream_t stream) {
    const float* xyz = (const float*)d_in[0];
    int n = in_sizes[0] / 3;

    const size_t CSZ = (size_t)CHW * CDIM;
    const size_t FSZ = (size_t)FHW * CDIM;
    const size_t PLANE_UINTS = (3 * CSZ + 3 * FSZ) / 2;   // packed bf16 pairs

    unsigned* planesb = (unsigned*)d_ws;
    int*      cells   = (int*)(planesb + PLANE_UINTS);
    float4*   sortedg = (float4*)((char*)(cells) + (size_t)NCELL * 4);

    dim3 blk(256);
    PlanePtrs pp;
    for (int k = 0; k < 6; ++k) pp.p[k] = (const float*)d_in[1 + k];

    zero_cells<<<NCELL / 4 / 256, blk, 0, stream>>>((int4*)cells);

    int histblk = (n + 1023) / 1024;   // 4 pts/thread
    transpose_hist<<<TRB + histblk, blk, 0, stream>>>(pp, planesb, xyz, cells, n);

    scan_cells<<<1, 1024, 0, stream>>>(cells);
    scatter_kernel<<<histblk, blk, 0, stream>>>(xyz, cells, sortedg, n);

    int nblk = (n + 31) / 32;          // 32 points per block
    triplane_sample<<<nblk, blk, 0, stream>>>(sortedg, planesb, (float*)d_out, n);
}